// Round 5
// baseline (80.614 us; speedup 1.0000x reference)
//
#include <hip/hip_runtime.h>
#include <hip/hip_bf16.h>

typedef __bf16 bf16_t;
typedef __bf16 bf16x8 __attribute__((ext_vector_type(8)));
typedef float f32x4 __attribute__((ext_vector_type(4)));

#define MFMA(A, B, C) __builtin_amdgcn_mfma_f32_16x16x32_bf16(A, B, C, 0, 0, 0)

// async global->LDS, 16B per lane; LDS dest is wave-uniform base + lane*16.
#define GLL16(g, l) __builtin_amdgcn_global_load_lds(                      \
    (const __attribute__((address_space(1))) void*)(g),                    \
    (__attribute__((address_space(3))) void*)(l), 16, 0, 0)

static __device__ __forceinline__ bf16x8 cvt8p(const float4& a, const float4& b, float sc) {
  bf16x8 o;
  o[0] = (bf16_t)(a.x * sc); o[1] = (bf16_t)(a.y * sc);
  o[2] = (bf16_t)(a.z * sc); o[3] = (bf16_t)(a.w * sc);
  o[4] = (bf16_t)(b.x * sc); o[5] = (bf16_t)(b.y * sc);
  o[6] = (bf16_t)(b.z * sc); o[7] = (bf16_t)(b.w * sc);
  return o;
}

// ---------------- QKV projection GEMM: fp32 inputs, cvt fused into staging --
// 128x64 tile, BK=64, NT. Single-barrier double-buffered pipeline:
//   barrier -> (write staged regs to LDS[nxt], load k+2 regs) -> MFMA on cur.
__global__ __launch_bounds__(256) void gemm_qkv(
    const float* __restrict__ xq, const float* __restrict__ xk, const float* __restrict__ xv,
    const float* __restrict__ Wq, const float* __restrict__ Wk, const float* __restrict__ Wv,
    bf16_t* __restrict__ qo, bf16_t* __restrict__ ko, bf16_t* __restrict__ vt)
{
  __shared__ __align__(16) bf16_t As[2][128 * 64];
  __shared__ __align__(16) bf16_t Bs[2][64 * 64];
  const int z = blockIdx.z;
  const float* A = z == 0 ? xq : z == 1 ? xk : xv;
  const float* W = z == 0 ? Wq : z == 1 ? Wk : Wv;
  const float wsc = z < 2 ? 0.125f : 1.0f;   // q,k each pre-scaled 1/sqrt(d)
  const int bm = blockIdx.x * 128, bn = blockIdx.y * 64;
  const int tid = threadIdx.x, lane = tid & 63, wave = tid >> 6;
  const int l15 = lane & 15, l4 = lane >> 4, l7 = l15 & 7;
  const int wm = (wave >> 1) * 64, wn = (wave & 1) * 32;

  float4 ra[4][2], rb[2][2];
  auto aload = [&](int k0) {
#pragma unroll
    for (int i = 0; i < 4; ++i) {
      const int id = i * 256 + tid, row = id >> 3, c = id & 7;
      const float* p = A + (size_t)(bm + row) * 1024 + k0 + 8 * c;
      ra[i][0] = *(const float4*)p; ra[i][1] = *(const float4*)(p + 4);
    }
  };
  auto bload = [&](int k0) {
#pragma unroll
    for (int i = 0; i < 2; ++i) {
      const int id = i * 256 + tid, row = id >> 3, c = id & 7;
      const float* p = W + (size_t)(bn + row) * 1024 + k0 + 8 * c;
      rb[i][0] = *(const float4*)p; rb[i][1] = *(const float4*)(p + 4);
    }
  };
  auto abwrite = [&](int buf) {
#pragma unroll
    for (int i = 0; i < 4; ++i) {
      const int id = i * 256 + tid, row = id >> 3, c = id & 7;
      *(bf16x8*)(&As[buf][row * 64 + 8 * (c ^ (row & 7))]) = cvt8p(ra[i][0], ra[i][1], 1.0f);
    }
#pragma unroll
    for (int i = 0; i < 2; ++i) {
      const int id = i * 256 + tid, row = id >> 3, c = id & 7;
      *(bf16x8*)(&Bs[buf][row * 64 + 8 * (c ^ (row & 7))]) = cvt8p(rb[i][0], rb[i][1], wsc);
    }
  };

  f32x4 acc[4][2] = {};
  aload(0); bload(0);
  abwrite(0);
  aload(64); bload(64);           // depth-2 register prefetch (k=64)
#pragma unroll
  for (int s = 0; s < 16; ++s) {
    __syncthreads();              // buf[s&1] staged (last iter's writes drained)
    if (s + 1 < 16) {
      abwrite((s + 1) & 1);       // regs hold k+1; write other buffer
      if (s + 2 < 16) { aload((s + 2) * 64); bload((s + 2) * 64); }
    }
    const bf16_t* as = As[s & 1];
    const bf16_t* bs = Bs[s & 1];
#pragma unroll
    for (int ks = 0; ks < 2; ++ks) {
      bf16x8 af[4], bfr[2];
#pragma unroll
      for (int i = 0; i < 4; ++i)
        af[i] = *(const bf16x8*)(&as[(wm + i * 16 + l15) * 64 + 8 * ((ks * 4 + l4) ^ l7)]);
#pragma unroll
      for (int j = 0; j < 2; ++j)
        bfr[j] = *(const bf16x8*)(&bs[(wn + j * 16 + l15) * 64 + 8 * ((ks * 4 + l4) ^ l7)]);
#pragma unroll
      for (int i = 0; i < 4; ++i)
#pragma unroll
        for (int j = 0; j < 2; ++j)
          acc[i][j] = MFMA(af[i], bfr[j], acc[i][j]);
    }
  }

  if (z < 2) {
    bf16_t* C = z == 0 ? qo : ko;
#pragma unroll
    for (int i = 0; i < 4; ++i)
#pragma unroll
      for (int j = 0; j < 2; ++j)
#pragma unroll
        for (int r = 0; r < 4; ++r)
          C[(size_t)(bm + wm + i * 16 + 4 * l4 + r) * 1024 + bn + wn + j * 16 + l15] =
              (bf16_t)acc[i][j][r];
  } else {
#pragma unroll
    for (int i = 0; i < 4; ++i)
#pragma unroll
      for (int j = 0; j < 2; ++j)
#pragma unroll
        for (int r = 0; r < 4; ++r)
          vt[(size_t)(bn + wn + j * 16 + l15) * 2048 + bm + wm + i * 16 + 4 * l4 + r] =
              (bf16_t)acc[i][j][r];
  }
}

// ---------------- output GEMM: bf16 A via global_load_lds, fp32 W staged ----
__global__ __launch_bounds__(256) void gemm_out(
    const bf16_t* __restrict__ ctx, const float* __restrict__ Wo, float* __restrict__ out)
{
  __shared__ __align__(16) bf16_t As[2][128 * 64];
  __shared__ __align__(16) bf16_t Bs[2][64 * 64];
  const int bm = blockIdx.x * 128, bn = blockIdx.y * 64;
  const int tid = threadIdx.x, lane = tid & 63, wave = tid >> 6;
  const int l15 = lane & 15, l4 = lane >> 4, l7 = l15 & 7;
  const int wm = (wave >> 1) * 64, wn = (wave & 1) * 32;

  auto astage = [&](int buf, int k0) {   // linear LDS dest + pre-swizzled source
#pragma unroll
    for (int i = 0; i < 4; ++i) {
      const int id = i * 256 + tid, row = id >> 3, cph = id & 7;
      GLL16(ctx + (size_t)(bm + row) * 1024 + k0 + 8 * (cph ^ (row & 7)),
            &As[buf][(i * 256 + wave * 64) * 8]);
    }
  };
  float4 rb[2][2];
  auto bload = [&](int k0) {
#pragma unroll
    for (int i = 0; i < 2; ++i) {
      const int id = i * 256 + tid, row = id >> 3, c = id & 7;
      const float* p = Wo + (size_t)(bn + row) * 1024 + k0 + 8 * c;
      rb[i][0] = *(const float4*)p; rb[i][1] = *(const float4*)(p + 4);
    }
  };
  auto bwrite = [&](int buf) {
#pragma unroll
    for (int i = 0; i < 2; ++i) {
      const int id = i * 256 + tid, row = id >> 3, c = id & 7;
      *(bf16x8*)(&Bs[buf][row * 64 + 8 * (c ^ (row & 7))]) = cvt8p(rb[i][0], rb[i][1], 1.0f);
    }
  };

  f32x4 acc[4][2] = {};
  astage(0, 0); bload(0);
  bwrite(0);
  bload(64);
#pragma unroll
  for (int s = 0; s < 16; ++s) {
    __syncthreads();              // buf[s&1] ready (GLL + ds_writes drained)
    if (s + 1 < 16) {
      astage((s + 1) & 1, (s + 1) * 64);   // async, covered by this compute phase
      bwrite((s + 1) & 1);
      if (s + 2 < 16) bload((s + 2) * 64);
    }
    const bf16_t* as = As[s & 1];
    const bf16_t* bs = Bs[s & 1];
#pragma unroll
    for (int ks = 0; ks < 2; ++ks) {
      bf16x8 af[4], bfr[2];
#pragma unroll
      for (int i = 0; i < 4; ++i)
        af[i] = *(const bf16x8*)(&as[(wm + i * 16 + l15) * 64 + 8 * ((ks * 4 + l4) ^ l7)]);
#pragma unroll
      for (int j = 0; j < 2; ++j)
        bfr[j] = *(const bf16x8*)(&bs[(wn + j * 16 + l15) * 64 + 8 * ((ks * 4 + l4) ^ l7)]);
#pragma unroll
      for (int i = 0; i < 4; ++i)
#pragma unroll
        for (int j = 0; j < 2; ++j)
          acc[i][j] = MFMA(af[i], bfr[j], acc[i][j]);
    }
  }
#pragma unroll
  for (int i = 0; i < 4; ++i)
#pragma unroll
    for (int j = 0; j < 2; ++j)
#pragma unroll
      for (int r = 0; r < 4; ++r)
        out[(size_t)(bm + wm + i * 16 + 4 * l4 + r) * 1024 + bn + wn + j * 16 + l15] =
            acc[i][j][r];
}

// ---------------- attention: 256 blocks x 512 threads (8 waves) -------------
// barrier -> issue next loads -> process (loads in flight under compute) -> commit
__global__ __launch_bounds__(512) void attn512(
    const bf16_t* __restrict__ Qb, const bf16_t* __restrict__ Kb,
    const bf16_t* __restrict__ Vt, bf16_t* __restrict__ Ctx)
{
  __shared__ __align__(16) bf16_t Ks[2][128 * 64];   // [key][d], swizzled
  __shared__ __align__(16) bf16_t Vs[2][64 * 128];   // [d][key], swizzled
  __shared__ __align__(16) bf16_t Ps[8][16 * 64];    // per-wave P tile

  const int bid = blockIdx.x;
  const int h = 2 * (bid & 7) + ((bid >> 3) >> 4);
  const int jp = (bid >> 3) & 15;
  const int hoff = h * 64;
  const int tid = threadIdx.x;
  const int lane = tid & 63, wave = tid >> 6;
  const int g = wave & 3, kh = wave >> 2;
  const int l15 = lane & 15, l4 = lane >> 4;
  const int l7 = l15 & 7;

  const int qtA = jp, qtB = 31 - jp;
  const int qbA = qtA * 64, qbB = qtB * 64;
  const int nscA = qtA / 2 + 1, nscB = qtB / 2 + 1;

  const int qrA = qbA + g * 16 + l15, qrB = qbB + g * 16 + l15;
  bf16x8 qA0 = *(const bf16x8*)(Qb + (size_t)qrA * 1024 + hoff + 8 * l4);
  bf16x8 qA1 = *(const bf16x8*)(Qb + (size_t)qrA * 1024 + hoff + 32 + 8 * l4);
  bf16x8 qB0 = *(const bf16x8*)(Qb + (size_t)qrB * 1024 + hoff + 8 * l4);
  bf16x8 qB1 = *(const bf16x8*)(Qb + (size_t)qrB * 1024 + hoff + 32 + 8 * l4);

  f32x4 oA[4] = {}, oB[4] = {};
  float dA[4] = {0.f, 0.f, 0.f, 0.f}, dB[4] = {0.f, 0.f, 0.f, 0.f};

  bf16x8 rk[2], rv[2];
  auto issue = [&](int sc) {
    const int t0 = sc * 128;
#pragma unroll
    for (int i = 0; i < 2; ++i) {
      const int id = tid + 512 * i;
      const int kr = id >> 3, kc = id & 7;
      rk[i] = *(const bf16x8*)(Kb + (size_t)(t0 + kr) * 1024 + hoff + 8 * kc);
      const int vr = id >> 4, vc = id & 15;
      rv[i] = *(const bf16x8*)(Vt + (size_t)(hoff + vr) * 2048 + t0 + 8 * vc);
    }
  };
  auto commit = [&](int buf) {
#pragma unroll
    for (int i = 0; i < 2; ++i) {
      const int id = tid + 512 * i;
      const int kr = id >> 3, kc = id & 7;
      *(bf16x8*)(&Ks[buf][kr * 64 + 8 * (kc ^ (kr & 7))]) = rk[i];
      const int vr = id >> 4, vc = id & 15;
      *(bf16x8*)(&Vs[buf][vr * 128 + 8 * (vc ^ (vr & 7))]) = rv[i];
    }
  };

  auto process = [&](int sc, int cur, int qb, const bf16x8& q0, const bf16x8& q1,
                     f32x4 (&oacc)[4], float (&den)[4]) {
    if (128 * sc + 64 * kh > qb + g * 16 + 15) return;
    const int tb = 128 * sc + 64 * kh;
#pragma unroll
    for (int sub = 0; sub < 4; ++sub) {
      const int krow = 64 * kh + 16 * sub + l15;
      bf16x8 kf0 = *(const bf16x8*)(&Ks[cur][krow * 64 + 8 * (l4 ^ l7)]);
      bf16x8 kf1 = *(const bf16x8*)(&Ks[cur][krow * 64 + 8 * ((4 + l4) ^ l7)]);
      __builtin_amdgcn_s_setprio(1);
      f32x4 sv = {};
      sv = MFMA(q0, kf0, sv);
      sv = MFMA(q1, kf1, sv);
      __builtin_amdgcn_s_setprio(0);
      const int t = tb + 16 * sub + l15;
#pragma unroll
      for (int r = 0; r < 4; ++r) {
        const int qq = qb + g * 16 + 4 * l4 + r;
        const float p = (t <= qq) ? __expf(sv[r]) : 0.0f;
        const bf16_t pb = (bf16_t)p;
        den[r] += (float)pb;
        const int prow = 4 * l4 + r;
        const int pch = 2 * sub + (l15 >> 3);
        Ps[wave][prow * 64 + 8 * (pch ^ (prow & 7)) + l7] = pb;
      }
    }
    asm volatile("s_waitcnt lgkmcnt(0)" ::: "memory");
    __builtin_amdgcn_s_setprio(1);
#pragma unroll
    for (int ks = 0; ks < 2; ++ks) {
      bf16x8 pf = *(const bf16x8*)(&Ps[wave][l15 * 64 + 8 * ((ks * 4 + l4) ^ l7)]);
#pragma unroll
      for (int db = 0; db < 4; ++db) {
        bf16x8 vf = *(const bf16x8*)(&Vs[cur][(db * 16 + l15) * 128 + 64 * kh + 8 * ((ks * 4 + l4) ^ l7)]);
        oacc[db] = MFMA(pf, vf, oacc[db]);
      }
    }
    __builtin_amdgcn_s_setprio(0);
  };

  issue(0);
  commit(0);
  int cur = 0;
  for (int sc = 0; sc < nscB; ++sc) {
    const bool pre = (sc + 1 < nscB);
    __syncthreads();                 // buf[cur] staged; prev iter's reads done
    if (pre) issue(sc + 1);          // loads fly under the process phase
    process(sc, cur, qbB, qB0, qB1, oB, dB);
    if (sc < nscA) process(sc, cur, qbA, qA0, qA1, oA, dA);
    if (pre) commit(cur ^ 1);        // vmcnt satisfied by now; writes drain at next barrier
    cur ^= 1;
  }

  __syncthreads();
#pragma unroll
  for (int r = 0; r < 4; ++r)
#pragma unroll
    for (int m = 1; m < 16; m <<= 1) {
      dA[r] += __shfl_xor(dA[r], m, 64);
      dB[r] += __shfl_xor(dB[r], m, 64);
    }
  float* Os = (float*)(&Ks[0][0]);
  float* Ds = (float*)(&Vs[0][0]);
  if (kh == 1) {
#pragma unroll
    for (int r = 0; r < 4; ++r) {
      const int row = g * 16 + 4 * l4 + r;
#pragma unroll
      for (int db = 0; db < 4; ++db) {
        Os[(0 * 64 + row) * 64 + db * 16 + l15] = oA[db][r];
        Os[(1 * 64 + row) * 64 + db * 16 + l15] = oB[db][r];
      }
      if (l15 == 0) { Ds[0 * 64 + row] = dA[r]; Ds[1 * 64 + row] = dB[r]; }
    }
  }
  __syncthreads();
  if (kh == 0) {
#pragma unroll
    for (int r = 0; r < 4; ++r) {
      const int row = g * 16 + 4 * l4 + r;
      const float iA = 1.0f / (dA[r] + Ds[0 * 64 + row]);
      const float iB = 1.0f / (dB[r] + Ds[1 * 64 + row]);
#pragma unroll
      for (int db = 0; db < 4; ++db) {
        const float vA = oA[db][r] + Os[(0 * 64 + row) * 64 + db * 16 + l15];
        const float vB = oB[db][r] + Os[(1 * 64 + row) * 64 + db * 16 + l15];
        Ctx[(size_t)(qbA + row) * 1024 + hoff + db * 16 + l15] = (bf16_t)(vA * iA);
        Ctx[(size_t)(qbB + row) * 1024 + hoff + db * 16 + l15] = (bf16_t)(vB * iB);
      }
    }
  }
}

extern "C" void kernel_launch(void* const* d_in, const int* in_sizes, int n_in,
                              void* d_out, int out_size, void* d_ws, size_t ws_size,
                              hipStream_t stream)
{
  const float* query = (const float*)d_in[0];
  const float* key_  = (const float*)d_in[1];
  const float* value = (const float*)d_in[2];
  // d_in[3] = mask: exactly causal tril, reproduced from indices
  const float* Wq = (const float*)d_in[4];
  const float* Wk = (const float*)d_in[5];
  const float* Wv = (const float*)d_in[6];
  const float* Wo = (const float*)d_in[7];
  float* out = (float*)d_out;

  const size_t SE = (size_t)2048 * 1024;
  bf16_t* qo  = (bf16_t*)d_ws;      // Q projection [2048][1024] bf16
  bf16_t* ko  = qo + SE;            // K projection
  bf16_t* vt  = ko + SE;            // V transposed [1024][2048]
  bf16_t* ctx = vt + SE;            // attention output

  gemm_qkv<<<dim3(16, 16, 3), 256, 0, stream>>>(query, key_, value, Wq, Wk, Wv, qo, ko, vt);
  attn512<<<256, 512, 0, stream>>>(qo, ko, vt, ctx);
  gemm_out<<<dim3(16, 16), 256, 0, stream>>>(ctx, Wo, out);
}

// Round 6
// 75.642 us; speedup vs baseline: 1.0657x; 1.0657x over previous
//
#include <hip/hip_runtime.h>
#include <hip/hip_bf16.h>

typedef __bf16 bf16_t;
typedef __bf16 bf16x8 __attribute__((ext_vector_type(8)));
typedef float f32x4 __attribute__((ext_vector_type(4)));

#define MFMA(A, B, C) __builtin_amdgcn_mfma_f32_16x16x32_bf16(A, B, C, 0, 0, 0)

// async global->LDS, 16B per lane; LDS dest is wave-uniform base + lane*16.
#define GLL16(g, l) __builtin_amdgcn_global_load_lds(                      \
    (const __attribute__((address_space(1))) void*)(g),                    \
    (__attribute__((address_space(3))) void*)(l), 16, 0, 0)

// ---------------- fused fp32 -> bf16 convert (3 activations + 4 weights) ----
__global__ __launch_bounds__(256) void cvt_all(
    const float* __restrict__ q, const float* __restrict__ k, const float* __restrict__ v,
    const float* __restrict__ wq, const float* __restrict__ wk,
    const float* __restrict__ wv, const float* __restrict__ wo,
    bf16_t* __restrict__ xq, bf16_t* __restrict__ xk, bf16_t* __restrict__ xv,
    bf16_t* __restrict__ ywq, bf16_t* __restrict__ ywk,
    bf16_t* __restrict__ ywv, bf16_t* __restrict__ ywo)
{
  const long gid = (long)blockIdx.x * 256 + threadIdx.x;
  const float* s; bf16_t* d; long off; float sc = 1.0f;
  if (gid < 262144)       { s = q;  d = xq;  off = gid; }
  else if (gid < 524288)  { s = k;  d = xk;  off = gid - 262144; }
  else if (gid < 786432)  { s = v;  d = xv;  off = gid - 524288; }
  else if (gid < 917504)  { s = wq; d = ywq; off = gid - 786432;  sc = 0.125f; }
  else if (gid < 1048576) { s = wk; d = ywk; off = gid - 917504;  sc = 0.125f; }
  else if (gid < 1179648) { s = wv; d = ywv; off = gid - 1048576; }
  else                    { s = wo; d = ywo; off = gid - 1179648; }
  const float* p = s + off * 8;
  float4 a = *(const float4*)p, b = *(const float4*)(p + 4);
  bf16x8 o;
  o[0] = (bf16_t)(a.x * sc); o[1] = (bf16_t)(a.y * sc);
  o[2] = (bf16_t)(a.z * sc); o[3] = (bf16_t)(a.w * sc);
  o[4] = (bf16_t)(b.x * sc); o[5] = (bf16_t)(b.y * sc);
  o[6] = (bf16_t)(b.z * sc); o[7] = (bf16_t)(b.w * sc);
  *(bf16x8*)(d + off * 8) = o;
}

// ---------------- GEMM core: 128x64 tile, BK=64, NT, all-bf16 ---------------
// global_load_lds staging (pre-swizzled source, linear dest, swizzled read).
// T3 single-barrier pipeline: barrier -> stage(next, async) -> compute(cur);
// the next barrier's vmcnt(0) drain is covered by the full MFMA phase.
__device__ __forceinline__ void gemm_core(const bf16_t* __restrict__ A,
                                          const bf16_t* __restrict__ W,
                                          int bm, int bn,
                                          bf16_t (&As)[2][128 * 64],
                                          bf16_t (&Bs)[2][64 * 64],
                                          f32x4 (&acc)[4][2])
{
  const int tid = threadIdx.x, lane = tid & 63, wave = tid >> 6;
  const int l15 = lane & 15, l4 = lane >> 4, l7 = l15 & 7;
  const int wm = (wave >> 1) * 64, wn = (wave & 1) * 32;

  auto stage = [&](int buf, int k0) {
#pragma unroll
    for (int i = 0; i < 4; ++i) {
      const int id = i * 256 + tid, row = id >> 3, cph = id & 7;
      GLL16(A + (size_t)(bm + row) * 1024 + k0 + 8 * (cph ^ (row & 7)),
            &As[buf][(i * 256 + wave * 64) * 8]);
    }
#pragma unroll
    for (int i = 0; i < 2; ++i) {
      const int id = i * 256 + tid, row = id >> 3, cph = id & 7;
      GLL16(W + (size_t)(bn + row) * 1024 + k0 + 8 * (cph ^ (row & 7)),
            &Bs[buf][(i * 256 + wave * 64) * 8]);
    }
  };

  stage(0, 0);
#pragma unroll
  for (int s = 0; s < 16; ++s) {
    __syncthreads();                  // drains stage issued LAST iter (full phase in flight)
    if (s + 1 < 16) stage((s + 1) & 1, (s + 1) * 64);   // async under this compute
    const bf16_t* as = As[s & 1];
    const bf16_t* bs = Bs[s & 1];
#pragma unroll
    for (int ks = 0; ks < 2; ++ks) {
      bf16x8 af[4], bfr[2];
#pragma unroll
      for (int i = 0; i < 4; ++i)
        af[i] = *(const bf16x8*)(&as[(wm + i * 16 + l15) * 64 + 8 * ((ks * 4 + l4) ^ l7)]);
#pragma unroll
      for (int j = 0; j < 2; ++j)
        bfr[j] = *(const bf16x8*)(&bs[(wn + j * 16 + l15) * 64 + 8 * ((ks * 4 + l4) ^ l7)]);
#pragma unroll
      for (int i = 0; i < 4; ++i)
#pragma unroll
        for (int j = 0; j < 2; ++j)
          acc[i][j] = MFMA(af[i], bfr[j], acc[i][j]);
    }
  }
}

__global__ __launch_bounds__(256) void gemm_qkv(
    const bf16_t* __restrict__ xq, const bf16_t* __restrict__ xk, const bf16_t* __restrict__ xv,
    const bf16_t* __restrict__ ywq, const bf16_t* __restrict__ ywk, const bf16_t* __restrict__ ywv,
    bf16_t* __restrict__ qo, bf16_t* __restrict__ ko, bf16_t* __restrict__ vt)
{
  __shared__ __align__(16) bf16_t As[2][128 * 64];
  __shared__ __align__(16) bf16_t Bs[2][64 * 64];
  const int z = blockIdx.z;
  const bf16_t* A = z == 0 ? xq : z == 1 ? xk : xv;
  const bf16_t* W = z == 0 ? ywq : z == 1 ? ywk : ywv;
  const int bm = blockIdx.x * 128, bn = blockIdx.y * 64;
  f32x4 acc[4][2] = {};
  gemm_core(A, W, bm, bn, As, Bs, acc);
  const int tid = threadIdx.x, lane = tid & 63, wave = tid >> 6;
  const int l15 = lane & 15, l4 = lane >> 4;
  const int wm = (wave >> 1) * 64, wn = (wave & 1) * 32;
  if (z < 2) {
    bf16_t* C = z == 0 ? qo : ko;
#pragma unroll
    for (int i = 0; i < 4; ++i)
#pragma unroll
      for (int j = 0; j < 2; ++j)
#pragma unroll
        for (int r = 0; r < 4; ++r)
          C[(size_t)(bm + wm + i * 16 + 4 * l4 + r) * 1024 + bn + wn + j * 16 + l15] =
              (bf16_t)acc[i][j][r];
  } else {
#pragma unroll
    for (int i = 0; i < 4; ++i)
#pragma unroll
      for (int j = 0; j < 2; ++j)
#pragma unroll
        for (int r = 0; r < 4; ++r)
          vt[(size_t)(bn + wn + j * 16 + l15) * 2048 + bm + wm + i * 16 + 4 * l4 + r] =
              (bf16_t)acc[i][j][r];
  }
}

__global__ __launch_bounds__(256) void gemm_out(
    const bf16_t* __restrict__ ctx, const bf16_t* __restrict__ ywo, float* __restrict__ out)
{
  __shared__ __align__(16) bf16_t As[2][128 * 64];
  __shared__ __align__(16) bf16_t Bs[2][64 * 64];
  const int bm = blockIdx.x * 128, bn = blockIdx.y * 64;
  f32x4 acc[4][2] = {};
  gemm_core(ctx, ywo, bm, bn, As, Bs, acc);
  const int tid = threadIdx.x, lane = tid & 63, wave = tid >> 6;
  const int l15 = lane & 15, l4 = lane >> 4;
  const int wm = (wave >> 1) * 64, wn = (wave & 1) * 32;
#pragma unroll
  for (int i = 0; i < 4; ++i)
#pragma unroll
    for (int j = 0; j < 2; ++j)
#pragma unroll
      for (int r = 0; r < 4; ++r)
        out[(size_t)(bm + wm + i * 16 + 4 * l4 + r) * 1024 + bn + wn + j * 16 + l15] =
            acc[i][j][r];
}

// ---------------- attention: 256 blocks x 512 threads (8 waves) -------------
// barrier -> issue next loads -> process (loads in flight under compute) -> commit
__global__ __launch_bounds__(512) void attn512(
    const bf16_t* __restrict__ Qb, const bf16_t* __restrict__ Kb,
    const bf16_t* __restrict__ Vt, bf16_t* __restrict__ Ctx)
{
  __shared__ __align__(16) bf16_t Ks[2][128 * 64];   // [key][d], swizzled
  __shared__ __align__(16) bf16_t Vs[2][64 * 128];   // [d][key], swizzled
  __shared__ __align__(16) bf16_t Ps[8][16 * 64];    // per-wave P tile

  const int bid = blockIdx.x;
  const int h = 2 * (bid & 7) + ((bid >> 3) >> 4);
  const int jp = (bid >> 3) & 15;
  const int hoff = h * 64;
  const int tid = threadIdx.x;
  const int lane = tid & 63, wave = tid >> 6;
  const int g = wave & 3, kh = wave >> 2;
  const int l15 = lane & 15, l4 = lane >> 4;
  const int l7 = l15 & 7;

  const int qtA = jp, qtB = 31 - jp;
  const int qbA = qtA * 64, qbB = qtB * 64;
  const int nscA = qtA / 2 + 1, nscB = qtB / 2 + 1;

  const int qrA = qbA + g * 16 + l15, qrB = qbB + g * 16 + l15;
  bf16x8 qA0 = *(const bf16x8*)(Qb + (size_t)qrA * 1024 + hoff + 8 * l4);
  bf16x8 qA1 = *(const bf16x8*)(Qb + (size_t)qrA * 1024 + hoff + 32 + 8 * l4);
  bf16x8 qB0 = *(const bf16x8*)(Qb + (size_t)qrB * 1024 + hoff + 8 * l4);
  bf16x8 qB1 = *(const bf16x8*)(Qb + (size_t)qrB * 1024 + hoff + 32 + 8 * l4);

  f32x4 oA[4] = {}, oB[4] = {};
  float dA[4] = {0.f, 0.f, 0.f, 0.f}, dB[4] = {0.f, 0.f, 0.f, 0.f};

  bf16x8 rk[2], rv[2];
  auto issue = [&](int sc) {
    const int t0 = sc * 128;
#pragma unroll
    for (int i = 0; i < 2; ++i) {
      const int id = tid + 512 * i;
      const int kr = id >> 3, kc = id & 7;
      rk[i] = *(const bf16x8*)(Kb + (size_t)(t0 + kr) * 1024 + hoff + 8 * kc);
      const int vr = id >> 4, vc = id & 15;
      rv[i] = *(const bf16x8*)(Vt + (size_t)(hoff + vr) * 2048 + t0 + 8 * vc);
    }
  };
  auto commit = [&](int buf) {
#pragma unroll
    for (int i = 0; i < 2; ++i) {
      const int id = tid + 512 * i;
      const int kr = id >> 3, kc = id & 7;
      *(bf16x8*)(&Ks[buf][kr * 64 + 8 * (kc ^ (kr & 7))]) = rk[i];
      const int vr = id >> 4, vc = id & 15;
      *(bf16x8*)(&Vs[buf][vr * 128 + 8 * (vc ^ (vr & 7))]) = rv[i];
    }
  };

  auto process = [&](int sc, int cur, int qb, const bf16x8& q0, const bf16x8& q1,
                     f32x4 (&oacc)[4], float (&den)[4]) {
    if (128 * sc + 64 * kh > qb + g * 16 + 15) return;
    const int tb = 128 * sc + 64 * kh;
#pragma unroll
    for (int sub = 0; sub < 4; ++sub) {
      const int krow = 64 * kh + 16 * sub + l15;
      bf16x8 kf0 = *(const bf16x8*)(&Ks[cur][krow * 64 + 8 * (l4 ^ l7)]);
      bf16x8 kf1 = *(const bf16x8*)(&Ks[cur][krow * 64 + 8 * ((4 + l4) ^ l7)]);
      __builtin_amdgcn_s_setprio(1);
      f32x4 sv = {};
      sv = MFMA(q0, kf0, sv);
      sv = MFMA(q1, kf1, sv);
      __builtin_amdgcn_s_setprio(0);
      const int t = tb + 16 * sub + l15;
#pragma unroll
      for (int r = 0; r < 4; ++r) {
        const int qq = qb + g * 16 + 4 * l4 + r;
        const float p = (t <= qq) ? __expf(sv[r]) : 0.0f;
        const bf16_t pb = (bf16_t)p;
        den[r] += (float)pb;
        const int prow = 4 * l4 + r;
        const int pch = 2 * sub + (l15 >> 3);
        Ps[wave][prow * 64 + 8 * (pch ^ (prow & 7)) + l7] = pb;
      }
    }
    asm volatile("s_waitcnt lgkmcnt(0)" ::: "memory");
    __builtin_amdgcn_s_setprio(1);
#pragma unroll
    for (int ks = 0; ks < 2; ++ks) {
      bf16x8 pf = *(const bf16x8*)(&Ps[wave][l15 * 64 + 8 * ((ks * 4 + l4) ^ l7)]);
#pragma unroll
      for (int db = 0; db < 4; ++db) {
        bf16x8 vf = *(const bf16x8*)(&Vs[cur][(db * 16 + l15) * 128 + 64 * kh + 8 * ((ks * 4 + l4) ^ l7)]);
        oacc[db] = MFMA(pf, vf, oacc[db]);
      }
    }
    __builtin_amdgcn_s_setprio(0);
  };

  issue(0);
  commit(0);
  int cur = 0;
  for (int sc = 0; sc < nscB; ++sc) {
    const bool pre = (sc + 1 < nscB);
    __syncthreads();                 // buf[cur] staged; prev iter's reads done
    if (pre) issue(sc + 1);          // loads fly under the process phase
    process(sc, cur, qbB, qB0, qB1, oB, dB);
    if (sc < nscA) process(sc, cur, qbA, qA0, qA1, oA, dA);
    if (pre) commit(cur ^ 1);        // vmcnt satisfied by now; writes drain at next barrier
    cur ^= 1;
  }

  __syncthreads();
#pragma unroll
  for (int r = 0; r < 4; ++r)
#pragma unroll
    for (int m = 1; m < 16; m <<= 1) {
      dA[r] += __shfl_xor(dA[r], m, 64);
      dB[r] += __shfl_xor(dB[r], m, 64);
    }
  float* Os = (float*)(&Ks[0][0]);
  float* Ds = (float*)(&Vs[0][0]);
  if (kh == 1) {
#pragma unroll
    for (int r = 0; r < 4; ++r) {
      const int row = g * 16 + 4 * l4 + r;
#pragma unroll
      for (int db = 0; db < 4; ++db) {
        Os[(0 * 64 + row) * 64 + db * 16 + l15] = oA[db][r];
        Os[(1 * 64 + row) * 64 + db * 16 + l15] = oB[db][r];
      }
      if (l15 == 0) { Ds[0 * 64 + row] = dA[r]; Ds[1 * 64 + row] = dB[r]; }
    }
  }
  __syncthreads();
  if (kh == 0) {
#pragma unroll
    for (int r = 0; r < 4; ++r) {
      const int row = g * 16 + 4 * l4 + r;
      const float iA = 1.0f / (dA[r] + Ds[0 * 64 + row]);
      const float iB = 1.0f / (dB[r] + Ds[1 * 64 + row]);
#pragma unroll
      for (int db = 0; db < 4; ++db) {
        const float vA = oA[db][r] + Os[(0 * 64 + row) * 64 + db * 16 + l15];
        const float vB = oB[db][r] + Os[(1 * 64 + row) * 64 + db * 16 + l15];
        Ctx[(size_t)(qbA + row) * 1024 + hoff + db * 16 + l15] = (bf16_t)(vA * iA);
        Ctx[(size_t)(qbB + row) * 1024 + hoff + db * 16 + l15] = (bf16_t)(vB * iB);
      }
    }
  }
}

extern "C" void kernel_launch(void* const* d_in, const int* in_sizes, int n_in,
                              void* d_out, int out_size, void* d_ws, size_t ws_size,
                              hipStream_t stream)
{
  const float* query = (const float*)d_in[0];
  const float* key_  = (const float*)d_in[1];
  const float* value = (const float*)d_in[2];
  // d_in[3] = mask: exactly causal tril, reproduced from indices
  const float* Wq = (const float*)d_in[4];
  const float* Wk = (const float*)d_in[5];
  const float* Wv = (const float*)d_in[6];
  const float* Wo = (const float*)d_in[7];
  float* out = (float*)d_out;

  const size_t SE = (size_t)2048 * 1024, EE = (size_t)1024 * 1024;
  bf16_t* xq  = (bf16_t*)d_ws;      // converted activations (bf16)
  bf16_t* xk  = xq + SE;
  bf16_t* xv  = xk + SE;
  bf16_t* wq  = xv + SE;            // converted weights (Wq,Wk pre-scaled 1/8)
  bf16_t* wk  = wq + EE;
  bf16_t* wv  = wk + EE;
  bf16_t* wo  = wv + EE;
  bf16_t* qo  = wo + EE;            // projections
  bf16_t* ko  = qo + SE;
  bf16_t* vt  = ko + SE;            // V transposed [1024][2048]
  bf16_t* ctx = vt + SE;            // attention output

  cvt_all<<<5120, 256, 0, stream>>>(query, key_, value, Wq, Wk, Wv, Wo,
                                    xq, xk, xv, wq, wk, wv, wo);
  gemm_qkv<<<dim3(16, 16, 3), 256, 0, stream>>>(xq, xk, xv, wq, wk, wv, qo, ko, vt);
  attn512<<<256, 512, 0, stream>>>(qo, ko, vt, ctx);
  gemm_out<<<dim3(16, 16), 256, 0, stream>>>(ctx, wo, out);
}